// Round 4
// baseline (468.985 us; speedup 1.0000x reference)
//
#include <hip/hip_runtime.h>
#include <hip/hip_bf16.h>
#include <math.h>

// Problem constants
#define N_E      16384
#define E_DIM    64
#define GROUPS   4
#define N_E_G    4096
#define NQ       16384     // B*H*W query vectors

// Output layout (element offsets into d_out, float32)
#define OFF_QUANT   0L
#define OFF_VQLOSS  4194304L
#define OFF_PERP    4194316L
#define OFF_MINENC  4194317L
#define OFF_IDX     71303181L

// Workspace layout (element offsets into d_ws as float*/int*)
#define WS_EN     0L          // normalized emb fp32 [4][4096][64]
#define WS_EN2    1048576L    // |e|^2 per code [16384]
#define WS_ENHI   1064960L    // bf16(en) ushort [4][4096][64] -> 524288 floats
#define WS_ZNR    1589248L    // normalized z fp32 [g][q][64]
#define WS_ZHI    5783552L    // bf16(zn) ushort [g][q][64] -> 2097152 floats
#define WS_HIST   7880704L    // int[4096] + int ctr

typedef float  float4v  __attribute__((ext_vector_type(4)));
typedef short  short8   __attribute__((ext_vector_type(8)));

static __device__ __forceinline__ ushort f2bf(float x) {
    union { __hip_bfloat16 h; ushort u; } cv; cv.h = __float2bfloat16(x);
    return cv.u;
}

// ---------------------------------------------------------------------------
// K0 (fused): blocks [0,4096) normalize embedding; blocks [4096,5120) norm z.
__global__ void norm_all_kernel(const float* __restrict__ emb,
                                const float* __restrict__ z,
                                float* __restrict__ en, float* __restrict__ en2,
                                ushort* __restrict__ ehi,
                                float* __restrict__ znr, ushort* __restrict__ zhi) {
    __shared__ float tile[64 * 65];
    __shared__ float rden[64];
    const int t = threadIdx.x;

    if (blockIdx.x < 4096) {
        // ---- embedding path: one wave per code
        int gid  = blockIdx.x * 256 + t;
        int code = gid >> 6;
        int lane = t & 63;
        float x = emb[code * 64 + lane];
        float ss = x * x;
        #pragma unroll
        for (int off = 32; off; off >>= 1) ss += __shfl_xor(ss, off, 64);
        float v = x / fmaxf(sqrtf(ss), 1e-12f);
        en[code * 64 + lane]  = v;
        ehi[code * 64 + lane] = f2bf(v);
        float s2 = v * v;
        #pragma unroll
        for (int off = 32; off; off >>= 1) s2 += __shfl_xor(s2, off, 64);
        if (lane == 0) en2[code] = s2;
        return;
    }

    // ---- z path: 64x64 LDS tile, read-once, coalesced transposed writes
    int bx2 = blockIdx.x - 4096;          // [0,1024)
    int g   = bx2 >> 8;
    int n0  = (bx2 & 255) * 64;
    int b   = n0 >> 10, hw0 = n0 & 1023;
    const float* src = z + (size_t)b * 262144 + (size_t)g * 65536 + hw0;

    for (int i = t; i < 4096; i += 256) {
        int d = i >> 6, nl = i & 63;
        tile[d * 65 + nl] = src[(size_t)d * 1024 + nl];
    }
    __syncthreads();

    if (t < 64) {
        float ss = 0.f;
        for (int d = 0; d < 64; ++d) {
            float x = tile[d * 65 + t];
            ss = fmaf(x, x, ss);
        }
        rden[t] = fmaxf(sqrtf(ss), 1e-12f);
    }
    __syncthreads();

    for (int i = t; i < 4096; i += 256) {
        int q = i >> 6, d = i & 63;
        float v = tile[d * 65 + q] / rden[q];
        size_t o = ((size_t)g * NQ + n0 + q) * 64 + d;
        znr[o] = v;
        zhi[o] = f2bf(v);
    }
}

// ---------------------------------------------------------------------------
// K1: bf16-hi MFMA candidate generation (barrier-free K-loop) + exact fp32
// rescore + quant/idx/min_encodings/perplexity outputs, all fused.
// TAU >= 2*E, E = worst-case |dot - bf16hi-dot| <= 2*2^-8*(1+eps) = 7.83e-3.
#define CAP  64
#define TAU  0.017f
__global__ __launch_bounds__(256, 2)
void vq_cand_kernel(const ushort* __restrict__ zhi, const ushort* __restrict__ ehi,
                    const float* __restrict__ znr, const float* __restrict__ en,
                    const float* __restrict__ en2, float* __restrict__ out,
                    int* __restrict__ hist, int* __restrict__ ctr) {
    __shared__ int   cnt[128];
    __shared__ int   cand[128 * CAP];   // 32 KB
    __shared__ int   bks[128];
    __shared__ float ps[256];
    __shared__ int   lastFlag;

    const int g  = 3 - blockIdx.y;      // heavy (g==3) blocks dispatch first
    const int q0 = blockIdx.x * 128;
    const int t  = threadIdx.x;
    const int wave = t >> 6, lane = t & 63;
    const int l15 = lane & 15, quad = lane >> 4;
    const int qhalf = wave & 1, chalf = wave >> 1;

    if (t < 128) cnt[t] = 0;

    // B-frags (queries, bf16-hi), registers for the whole kernel
    short8 bfrag[4][2];
    {
        const ushort* zq = zhi + ((size_t)g * NQ + q0 + qhalf * 64 + l15) * 64 + quad * 8;
        #pragma unroll
        for (int u = 0; u < 4; ++u)
            #pragma unroll
            for (int ks = 0; ks < 2; ++ks)
                bfrag[u][ks] = *(const short8*)(zq + u * 16 * 64 + ks * 32);
    }
    __syncthreads();   // cnt ready before first capture

    const ushort* abase = ehi + (size_t)g * N_E_G * 64
                        + (size_t)(chalf * 64 + l15) * 64 + quad * 8;

    float Mrun[4];
    #pragma unroll
    for (int u = 0; u < 4; ++u) Mrun[u] = -3.4e38f;

    short8 afA[4][2], afB[4][2];
    #pragma unroll
    for (int cs = 0; cs < 4; ++cs)
        #pragma unroll
        for (int ks = 0; ks < 2; ++ks)
            afA[cs][ks] = *(const short8*)(abase + (size_t)(cs * 16) * 64 + ks * 32);

    auto do_tile = [&](short8 (&A)[4][2], short8 (&P)[4][2], int tile) {
        if (tile + 1 < 32) {
            const ushort* p = abase + (size_t)((tile + 1) * 128) * 64;
            #pragma unroll
            for (int cs = 0; cs < 4; ++cs)
                #pragma unroll
                for (int ks = 0; ks < 2; ++ks)
                    P[cs][ks] = *(const short8*)(p + (size_t)(cs * 16) * 64 + ks * 32);
        }
        float4v acc[4][4];
        #pragma unroll
        for (int cs = 0; cs < 4; ++cs)
            #pragma unroll
            for (int u = 0; u < 4; ++u) {
                float4v zz = {0.f, 0.f, 0.f, 0.f};
                float4v tmp = __builtin_amdgcn_mfma_f32_16x16x32_bf16(
                                  A[cs][0], bfrag[u][0], zz, 0, 0, 0);
                acc[cs][u] = __builtin_amdgcn_mfma_f32_16x16x32_bf16(
                                  A[cs][1], bfrag[u][1], tmp, 0, 0, 0);
            }
        const int j0 = tile * 128;
        #pragma unroll
        for (int u = 0; u < 4; ++u) {
            float m = acc[0][u][0];
            #pragma unroll
            for (int cs = 0; cs < 4; ++cs)
                #pragma unroll
                for (int r = 0; r < 4; ++r) m = fmaxf(m, acc[cs][u][r]);
            float m2 = fmaxf(m, __shfl_xor(m, 16, 64));
            float m4 = fmaxf(m2, __shfl_xor(m2, 32, 64));
            Mrun[u] = fmaxf(Mrun[u], m4);
            float thr = Mrun[u] - TAU;
            if (m >= thr) {                    // rare
                int ql = qhalf * 64 + u * 16 + l15;
                #pragma unroll
                for (int cs = 0; cs < 4; ++cs)
                    #pragma unroll
                    for (int r = 0; r < 4; ++r)
                        if (acc[cs][u][r] >= thr) {
                            int cidx = j0 + chalf * 64 + cs * 16 + quad * 4 + r;
                            int slot = atomicAdd(&cnt[ql], 1);
                            if (slot < CAP) cand[ql * CAP + slot] = cidx;
                        }
            }
        }
    };

    for (int tt = 0; tt < 32; tt += 2) {
        do_tile(afA, afB, tt);
        do_tile(afB, afA, tt + 1);
    }
    __syncthreads();

    // exact fp32 rescore (verified ordering/tie-break: first-wins == min idx)
    if (t < 128) {
        int q = q0 + t;
        float za[64];
        const float4v* zp = (const float4v*)(znr + ((size_t)g * NQ + q) * 64);
        #pragma unroll
        for (int i = 0; i < 16; ++i) {
            float4v v = zp[i];
            za[i*4+0] = v[0]; za[i*4+1] = v[1]; za[i*4+2] = v[2]; za[i*4+3] = v[3];
        }
        int nc = cnt[t]; if (nc > CAP) nc = CAP;
        float best = -3.4e38f; int bk = 0x7fffffff;
        for (int s = 0; s < nc; ++s) {
            int c = cand[t * CAP + s];
            const float* ev = en + ((size_t)g * N_E_G + c) * 64;
            float a = 0.f;
            #pragma unroll
            for (int k = 0; k < 64; ++k) a = fmaf(za[k], ev[k], a);
            float d = 2.f * a - en2[g * N_E_G + c];
            if (d > best || (d == best && c < bk)) { best = d; bk = c; }
        }
        if (bk == 0x7fffffff) bk = 0;
        bks[t] = bk;
        out[OFF_IDX + (size_t)q * 4 + g] = (float)bk;
        if (g == 3) atomicAdd(&hist[bk], 1);
    }
    __syncthreads();

    // quant write, coalesced along hw
    for (int i = t; i < 128 * 64; i += 256) {
        int d = i >> 7, m = i & 127;
        int n = q0 + m, b = n >> 10, hw = n & 1023;
        out[OFF_QUANT + (size_t)b * 262144 + (size_t)(g * 64 + d) * 1024 + hw] =
            en[((size_t)g * N_E_G + bks[m]) * 64 + d];
    }

    if (g != 3) return;

    // ---- min_encodings row-block: zeros + embedded one (replaces memset)
    {
        float4v* dst = (float4v*)(out + OFF_MINENC + (size_t)q0 * N_E_G);
        for (int i = t; i < 128 * 1024; i += 256) {
            int row = i >> 10;            // 1024 float4 per row
            int c4  = i & 1023;
            float4v v = {0.f, 0.f, 0.f, 0.f};
            int b = bks[row];
            if ((b >> 2) == c4) v[b & 3] = 1.0f;
            dst[i] = v;
        }
    }

    // ---- last g==3 block computes perplexity + zeroes the 13-float slot
    __threadfence();
    if (t == 0) lastFlag = (atomicAdd(ctr, 1) == 127);
    __syncthreads();
    if (!lastFlag) return;

    float acc = 0.f;
    for (int k = t; k < N_E_G; k += 256) {
        float p = (float)atomicAdd(&hist[k], 0) * (1.0f / 16384.0f);
        acc += p * logf(p + 1e-10f);
    }
    ps[t] = acc;
    __syncthreads();
    for (int o = 128; o; o >>= 1) {
        if (t < o) ps[t] += ps[t + o];
        __syncthreads();
    }
    if (t < 12) out[OFF_VQLOSS + t] = 0.f;
    if (t == 0) out[OFF_PERP] = expf(-ps[0]);
}

// ---------------------------------------------------------------------------
extern "C" void kernel_launch(void* const* d_in, const int* in_sizes, int n_in,
                              void* d_out, int out_size, void* d_ws, size_t ws_size,
                              hipStream_t stream) {
    const float* z_groups = (const float*)d_in[0];
    const float* emb      = (const float*)d_in[1];
    float* out = (float*)d_out;
    float* ws  = (float*)d_ws;

    float*  en   = ws + WS_EN;
    float*  en2  = ws + WS_EN2;
    ushort* ehi  = (ushort*)(ws + WS_ENHI);
    float*  znr  = ws + WS_ZNR;
    ushort* zhi  = (ushort*)(ws + WS_ZHI);
    int*    hist = (int*)(ws + WS_HIST);
    int*    ctr  = hist + N_E_G;

    hipMemsetAsync(hist, 0, (N_E_G + 1) * sizeof(int), stream);

    norm_all_kernel<<<4096 + 1024, 256, 0, stream>>>(emb, z_groups,
                                                     en, en2, ehi, znr, zhi);

    vq_cand_kernel<<<dim3(NQ / 128, GROUPS), 256, 0, stream>>>(
        zhi, ehi, znr, en, en2, out, hist, ctr);
}

// Round 5
// 402.507 us; speedup vs baseline: 1.1652x; 1.1652x over previous
//
#include <hip/hip_runtime.h>
#include <hip/hip_bf16.h>
#include <math.h>

// Problem constants
#define N_E      16384
#define E_DIM    64
#define GROUPS   4
#define N_E_G    4096
#define NQ       16384     // B*H*W query vectors

// Output layout (element offsets into d_out, float32)
#define OFF_QUANT   0L
#define OFF_VQLOSS  4194304L
#define OFF_PERP    4194316L
#define OFF_MINENC  4194317L
#define OFF_IDX     71303181L
// zero region [OFF_VQLOSS, OFF_IDX): 67,108,877 floats; aligned start.
// 512 slices x 32768 float4 cover 67,108,864; 13-float tail handled by slice 0.

// Workspace layout (element offsets into d_ws as float*/int*)
#define WS_EN     0L          // normalized emb fp32 [4][4096][64]
#define WS_EN2    1048576L    // |e|^2 per code [16384]
#define WS_ENHI   1064960L    // bf16(en) ushort [4][4096][64] -> 524288 floats
#define WS_ZNR    1589248L    // normalized z fp32 [g][q][64]
#define WS_ZHI    5783552L    // bf16(zn) ushort [g][q][64] -> 2097152 floats
#define WS_HIST   7880704L    // int[4096]
#define WS_IDX3   7884800L    // int[16384]

typedef float  float4v  __attribute__((ext_vector_type(4)));
typedef short  short8   __attribute__((ext_vector_type(8)));

static __device__ __forceinline__ ushort f2bf(float x) {
    union { __hip_bfloat16 h; ushort u; } cv; cv.h = __float2bfloat16(x);
    return cv.u;
}

// ---------------------------------------------------------------------------
// K0 (fused): blocks [0,4096) normalize embedding; blocks [4096,5120) norm z.
__global__ void norm_all_kernel(const float* __restrict__ emb,
                                const float* __restrict__ z,
                                float* __restrict__ en, float* __restrict__ en2,
                                ushort* __restrict__ ehi,
                                float* __restrict__ znr, ushort* __restrict__ zhi) {
    __shared__ float tile[64 * 65];
    __shared__ float rden[64];
    const int t = threadIdx.x;

    if (blockIdx.x < 4096) {
        // ---- embedding path: one wave per code
        int gid  = blockIdx.x * 256 + t;
        int code = gid >> 6;
        int lane = t & 63;
        float x = emb[code * 64 + lane];
        float ss = x * x;
        #pragma unroll
        for (int off = 32; off; off >>= 1) ss += __shfl_xor(ss, off, 64);
        float v = x / fmaxf(sqrtf(ss), 1e-12f);
        en[code * 64 + lane]  = v;
        ehi[code * 64 + lane] = f2bf(v);
        float s2 = v * v;
        #pragma unroll
        for (int off = 32; off; off >>= 1) s2 += __shfl_xor(s2, off, 64);
        if (lane == 0) en2[code] = s2;
        return;
    }

    // ---- z path: 64x64 LDS tile, read-once, coalesced transposed writes
    int bx2 = blockIdx.x - 4096;          // [0,1024)
    int g   = bx2 >> 8;
    int n0  = (bx2 & 255) * 64;
    int b   = n0 >> 10, hw0 = n0 & 1023;
    const float* src = z + (size_t)b * 262144 + (size_t)g * 65536 + hw0;

    for (int i = t; i < 4096; i += 256) {
        int d = i >> 6, nl = i & 63;
        tile[d * 65 + nl] = src[(size_t)d * 1024 + nl];
    }
    __syncthreads();

    if (t < 64) {
        float ss = 0.f;
        for (int d = 0; d < 64; ++d) {
            float x = tile[d * 65 + t];
            ss = fmaf(x, x, ss);
        }
        rden[t] = fmaxf(sqrtf(ss), 1e-12f);
    }
    __syncthreads();

    for (int i = t; i < 4096; i += 256) {
        int q = i >> 6, d = i & 63;
        float v = tile[d * 65 + q] / rden[q];
        size_t o = ((size_t)g * NQ + n0 + q) * 64 + d;
        znr[o] = v;
        zhi[o] = f2bf(v);
    }
}

// ---------------------------------------------------------------------------
// K1: bf16-hi MFMA candidate generation (barrier-free K-loop) + exact fp32
// rescore + quant/idx writes. Each block also zero-fills a flat 512 KB slice
// of [OFF_VQLOSS, OFF_IDX), 4 float4-stores per K-tile, issued AFTER the
// prefetch loads so they ride under MFMA latency without extending vmcnt
// waits. Ones + perplexity go in a stream-ordered finalize kernel (writing
// them here would race other blocks' zero-fill).
// TAU >= 2*E, E = worst-case |dot - bf16hi-dot| <= 2*2^-8*(1+eps) = 7.83e-3.
#define CAP  64
#define TAU  0.017f
__global__ __launch_bounds__(256, 2)
void vq_cand_kernel(const ushort* __restrict__ zhi, const ushort* __restrict__ ehi,
                    const float* __restrict__ znr, const float* __restrict__ en,
                    const float* __restrict__ en2, float* __restrict__ out,
                    int* __restrict__ hist, int* __restrict__ idx3) {
    __shared__ int    cnt[128];
    __shared__ ushort cand[128 * CAP];   // 16 KB
    __shared__ int    bks[128];

    const int g  = blockIdx.y;
    const int q0 = blockIdx.x * 128;
    const int t  = threadIdx.x;
    const int wave = t >> 6, lane = t & 63;
    const int l15 = lane & 15, quad = lane >> 4;
    const int qhalf = wave & 1, chalf = wave >> 1;

    const int sliceId = blockIdx.y * (NQ / 128) + blockIdx.x;   // 0..511
    float4v* fill4 = (float4v*)(out + OFF_VQLOSS) + (size_t)sliceId * 32768;

    if (t < 128) cnt[t] = 0;

    // B-frags (queries, bf16-hi), registers for the whole kernel
    short8 bfrag[4][2];
    {
        const ushort* zq = zhi + ((size_t)g * NQ + q0 + qhalf * 64 + l15) * 64 + quad * 8;
        #pragma unroll
        for (int u = 0; u < 4; ++u)
            #pragma unroll
            for (int ks = 0; ks < 2; ++ks)
                bfrag[u][ks] = *(const short8*)(zq + u * 16 * 64 + ks * 32);
    }
    __syncthreads();   // cnt ready before first capture

    const ushort* abase = ehi + (size_t)g * N_E_G * 64
                        + (size_t)(chalf * 64 + l15) * 64 + quad * 8;

    float Mrun[4];
    #pragma unroll
    for (int u = 0; u < 4; ++u) Mrun[u] = -3.4e38f;

    short8 afA[4][2], afB[4][2];
    #pragma unroll
    for (int cs = 0; cs < 4; ++cs)
        #pragma unroll
        for (int ks = 0; ks < 2; ++ks)
            afA[cs][ks] = *(const short8*)(abase + (size_t)(cs * 16) * 64 + ks * 32);

    auto do_tile = [&](short8 (&A)[4][2], short8 (&P)[4][2], int tile) {
        if (tile + 1 < 32) {
            const ushort* p = abase + (size_t)((tile + 1) * 128) * 64;
            #pragma unroll
            for (int cs = 0; cs < 4; ++cs)
                #pragma unroll
                for (int ks = 0; ks < 2; ++ks)
                    P[cs][ks] = *(const short8*)(p + (size_t)(cs * 16) * 64 + ks * 32);
        }
        // zero-fill slice: 4 float4 stores per tile, after the prefetch loads
        {
            const float4v z4 = {0.f, 0.f, 0.f, 0.f};
            #pragma unroll
            for (int r = 0; r < 4; ++r)
                fill4[(size_t)(tile * 4 + r) * 256 + t] = z4;
        }
        float4v acc[4][4];
        #pragma unroll
        for (int cs = 0; cs < 4; ++cs)
            #pragma unroll
            for (int u = 0; u < 4; ++u) {
                float4v zz = {0.f, 0.f, 0.f, 0.f};
                float4v tmp = __builtin_amdgcn_mfma_f32_16x16x32_bf16(
                                  A[cs][0], bfrag[u][0], zz, 0, 0, 0);
                acc[cs][u] = __builtin_amdgcn_mfma_f32_16x16x32_bf16(
                                  A[cs][1], bfrag[u][1], tmp, 0, 0, 0);
            }
        const int j0 = tile * 128;
        #pragma unroll
        for (int u = 0; u < 4; ++u) {
            float m = acc[0][u][0];
            #pragma unroll
            for (int cs = 0; cs < 4; ++cs)
                #pragma unroll
                for (int r = 0; r < 4; ++r) m = fmaxf(m, acc[cs][u][r]);
            float m2 = fmaxf(m, __shfl_xor(m, 16, 64));
            float m4 = fmaxf(m2, __shfl_xor(m2, 32, 64));
            Mrun[u] = fmaxf(Mrun[u], m4);
            float thr = Mrun[u] - TAU;
            if (m >= thr) {                    // rare
                int ql = qhalf * 64 + u * 16 + l15;
                #pragma unroll
                for (int cs = 0; cs < 4; ++cs)
                    #pragma unroll
                    for (int r = 0; r < 4; ++r)
                        if (acc[cs][u][r] >= thr) {
                            int cidx = j0 + chalf * 64 + cs * 16 + quad * 4 + r;
                            int slot = atomicAdd(&cnt[ql], 1);
                            if (slot < CAP) cand[ql * CAP + slot] = (ushort)cidx;
                        }
            }
        }
    };

    for (int tt = 0; tt < 32; tt += 2) {
        do_tile(afA, afB, tt);
        do_tile(afB, afA, tt + 1);
    }

    // 13-float tail of the zero region (unaligned remainder)
    if (sliceId == 0 && t < 13) out[OFF_VQLOSS + 67108864L + t] = 0.f;
    __syncthreads();

    // exact fp32 rescore (verified ordering/tie-break: first-wins == min idx)
    if (t < 128) {
        int q = q0 + t;
        float za[64];
        const float4v* zp = (const float4v*)(znr + ((size_t)g * NQ + q) * 64);
        #pragma unroll
        for (int i = 0; i < 16; ++i) {
            float4v v = zp[i];
            za[i*4+0] = v[0]; za[i*4+1] = v[1]; za[i*4+2] = v[2]; za[i*4+3] = v[3];
        }
        int nc = cnt[t]; if (nc > CAP) nc = CAP;
        float best = -3.4e38f; int bk = 0x7fffffff;
        for (int s = 0; s < nc; ++s) {
            int c = cand[t * CAP + s];
            const float* ev = en + ((size_t)g * N_E_G + c) * 64;
            float a = 0.f;
            #pragma unroll
            for (int k = 0; k < 64; ++k) a = fmaf(za[k], ev[k], a);
            float d = 2.f * a - en2[g * N_E_G + c];
            if (d > best || (d == best && c < bk)) { best = d; bk = c; }
        }
        if (bk == 0x7fffffff) bk = 0;
        bks[t] = bk;
        out[OFF_IDX + (size_t)q * 4 + g] = (float)bk;
        if (g == 3) {
            idx3[q] = bk;
            atomicAdd(&hist[bk], 1);
        }
    }
    __syncthreads();

    // quant write, coalesced along hw
    for (int i = t; i < 128 * 64; i += 256) {
        int d = i >> 7, m = i & 127;
        int n = q0 + m, b = n >> 10, hw = n & 1023;
        out[OFF_QUANT + (size_t)b * 262144 + (size_t)(g * 64 + d) * 1024 + hw] =
            en[((size_t)g * N_E_G + bks[m]) * 64 + d];
    }
}

// ---------------------------------------------------------------------------
// K2: scatter ones (64 blocks) + perplexity (block 64). Stream-ordered after
// vq_cand, so the zero-fill is complete and hist is final.
__global__ void finalize_kernel(const int* __restrict__ idx3,
                                const int* __restrict__ hist,
                                float* __restrict__ out) {
    if (blockIdx.x < 64) {
        int r = blockIdx.x * 256 + threadIdx.x;
        out[OFF_MINENC + (size_t)r * N_E_G + idx3[r]] = 1.0f;
        return;
    }
    __shared__ float s[256];
    int t = threadIdx.x;
    float acc = 0.f;
    for (int k = t; k < N_E_G; k += 256) {
        float p = (float)hist[k] * (1.0f / 16384.0f);
        acc += p * logf(p + 1e-10f);
    }
    s[t] = acc;
    __syncthreads();
    for (int o = 128; o; o >>= 1) {
        if (t < o) s[t] += s[t + o];
        __syncthreads();
    }
    if (t == 0) out[OFF_PERP] = expf(-s[0]);
}

// ---------------------------------------------------------------------------
extern "C" void kernel_launch(void* const* d_in, const int* in_sizes, int n_in,
                              void* d_out, int out_size, void* d_ws, size_t ws_size,
                              hipStream_t stream) {
    const float* z_groups = (const float*)d_in[0];
    const float* emb      = (const float*)d_in[1];
    float* out = (float*)d_out;
    float* ws  = (float*)d_ws;

    float*  en   = ws + WS_EN;
    float*  en2  = ws + WS_EN2;
    ushort* ehi  = (ushort*)(ws + WS_ENHI);
    float*  znr  = ws + WS_ZNR;
    ushort* zhi  = (ushort*)(ws + WS_ZHI);
    int*    hist = (int*)(ws + WS_HIST);
    int*    idx3 = (int*)(ws + WS_IDX3);

    hipMemsetAsync(hist, 0, N_E_G * sizeof(int), stream);

    norm_all_kernel<<<4096 + 1024, 256, 0, stream>>>(emb, z_groups,
                                                     en, en2, ehi, znr, zhi);

    vq_cand_kernel<<<dim3(NQ / 128, GROUPS), 256, 0, stream>>>(
        zhi, ehi, znr, en, en2, out, hist, idx3);

    finalize_kernel<<<65, 256, 0, stream>>>(idx3, hist, out);
}